// Round 2
// baseline (332.832 us; speedup 1.0000x reference)
//
#include <hip/hip_runtime.h>
#include <math.h>

#define T_SEQ 4096
#define BATCH 8
#define DM    512
#define NH    8
#define HD    64
#define RANK  128
#define NCHUNK 8
#define MTOT  (BATCH * T_SEQ)    /* 32768 */
#define BK 64

typedef unsigned int u32;
typedef unsigned short u16;
using bf16x8  = __attribute__((ext_vector_type(8))) __bf16;
using floatx4 = __attribute__((ext_vector_type(4))) float;

__device__ __forceinline__ u16 f2bf(float f) {   // RNE, finite inputs
  u32 u = __float_as_uint(f);
  u32 r = (u + 0x7FFFu + ((u >> 16) & 1u)) >> 16;
  return (u16)r;
}
// hi/lo bf16 split: f == hi + lo to ~17 mantissa bits
__device__ __forceinline__ void hilo(float f, u16& h, u16& l) {
  h = f2bf(f);
  float hf = __uint_as_float(((u32)h) << 16);
  l = f2bf(f - hf);
}
__device__ __forceinline__ float elu1(float x) {
  return (x > 0.f) ? x + 1.f : expf(x);
}
__device__ __forceinline__ void async16(void* lds, const void* g) {
  __builtin_amdgcn_global_load_lds(
      (const __attribute__((address_space(1))) u32*)g,
      (__attribute__((address_space(3))) u32*)lds, 16, 0, 0);
}
// LDS rows are 128 B (64 u16), 16B-chunk XOR-swizzled by (row&7).
__device__ __forceinline__ bf16x8 fragld(const u16* base, int row, int kk, int quad) {
  int ch = (kk * 4 + quad) ^ (row & 7);
  return *(const bf16x8*)((const char*)base + row * 128 + ch * 16);
}
// LDS rows are 256 B (128 u16), 16 chunks, XOR-swizzled by (row&7) (low 3 bits).
__device__ __forceinline__ bf16x8 fragldA(const u16* base, int row, int gc) {
  int ch = gc ^ (row & 7);
  return *(const bf16x8*)((const char*)base + row * 256 + ch * 16);
}

// ---------------- cos/sin table (double precision, matches np ref) ----------
__global__ void cs_kernel(float2* __restrict__ cs) {
  int i = blockIdx.x * 256 + threadIdx.x;
  if (i >= T_SEQ * 32) return;
  int t = i >> 5, d = i & 31;
  double freq = pow(10000.0, -(double)d / 32.0);
  double a = (double)t * freq;
  cs[i] = make_float2((float)cos(a), (float)sin(a));
}

// ---------------- pack fp32 -> bf16 -----------------------------------------
__global__ __launch_bounds__(256) void pack_bf16(const float* __restrict__ x,
                                                 u16* __restrict__ y) {
  int i = blockIdx.x * 256 + threadIdx.x;
  const float4 v = ((const float4*)x)[i];
  ushort4 o;
  o.x = f2bf(v.x); o.y = f2bf(v.y); o.z = f2bf(v.z); o.w = f2bf(v.w);
  ((ushort4*)y)[i] = o;
}

// ---------------- W (KxN fp32) -> WT (NxK bf16) -----------------------------
__global__ __launch_bounds__(256) void transpose_cast(const float* __restrict__ W,
                                                      u16* __restrict__ WT,
                                                      int K, int N) {
  __shared__ float t[32][33];
  int kb = blockIdx.x * 32, nb = blockIdx.y * 32;
  int tx = threadIdx.x & 31, tg = threadIdx.x >> 5;
#pragma unroll
  for (int i = 0; i < 4; i++)
    t[tg * 4 + i][tx] = W[(size_t)(kb + tg * 4 + i) * N + nb + tx];
  __syncthreads();
#pragma unroll
  for (int i = 0; i < 4; i++)
    WT[(size_t)(nb + tg * 4 + i) * K + kb + tx] = f2bf(t[tx][tg * 4 + i]);
}

// ---------------- W (KxN fp32) -> WT hi/lo (NxK bf16 pair) ------------------
__global__ __launch_bounds__(256) void transpose_cast_hilo(
    const float* __restrict__ W, u16* __restrict__ WTh, u16* __restrict__ WTl,
    int K, int N) {
  __shared__ float t[32][33];
  int kb = blockIdx.x * 32, nb = blockIdx.y * 32;
  int tx = threadIdx.x & 31, tg = threadIdx.x >> 5;
#pragma unroll
  for (int i = 0; i < 4; i++)
    t[tg * 4 + i][tx] = W[(size_t)(kb + tg * 4 + i) * N + nb + tx];
  __syncthreads();
#pragma unroll
  for (int i = 0; i < 4; i++) {
    u16 h, l;
    hilo(t[tx][tg * 4 + i], h, l);
    WTh[(size_t)(nb + tg * 4 + i) * K + kb + tx] = h;
    WTl[(size_t)(nb + tg * 4 + i) * K + kb + tx] = l;
  }
}

// ---------------- bf16 MFMA GEMM: C = A @ BT^T + bias (r1-proven) -----------
template <bool BF16OUT>
__global__ __launch_bounds__(256) void gemm_bf16_bt(
    const u16* __restrict__ A, const u16* __restrict__ BT,
    const float* __restrict__ bias, void* __restrict__ Cv,
    int M, int N, int K) {
  __shared__ u16 As[128 * BK];
  __shared__ u16 Bs[128 * BK];
  const int tid = threadIdx.x;
  const int lane = tid & 63, w = tid >> 6;
  const int m0 = blockIdx.y * 128, n0 = blockIdx.x * 128;
  const int wm = (w & 1) * 64, wn = (w >> 1) * 64;
  const int srow = lane >> 3, schunk = lane & 7;
  const int lane15 = lane & 15, quad = lane >> 4;
  floatx4 acc[4][4] = {};
  for (int kt = 0; kt < K; kt += BK) {
    __syncthreads();
#pragma unroll
    for (int i = 0; i < 4; i++) {
      int R = (w * 4 + i) * 8 + srow;
      int cg = schunk ^ (R & 7);
      async16((char*)As + (w * 4 + i) * 1024,
              (const char*)A + ((size_t)(m0 + R) * K + kt) * 2 + cg * 16);
      async16((char*)Bs + (w * 4 + i) * 1024,
              (const char*)BT + ((size_t)(n0 + R) * K + kt) * 2 + cg * 16);
    }
    __syncthreads();
#pragma unroll
    for (int kk = 0; kk < 2; kk++) {
      bf16x8 af[4], bfr[4];
#pragma unroll
      for (int mi = 0; mi < 4; mi++) af[mi] = fragld(As, wm + mi * 16 + lane15, kk, quad);
#pragma unroll
      for (int ni = 0; ni < 4; ni++) bfr[ni] = fragld(Bs, wn + ni * 16 + lane15, kk, quad);
#pragma unroll
      for (int mi = 0; mi < 4; mi++)
#pragma unroll
        for (int ni = 0; ni < 4; ni++)
          acc[mi][ni] = __builtin_amdgcn_mfma_f32_16x16x32_bf16(
              af[mi], bfr[ni], acc[mi][ni], 0, 0, 0);
    }
  }
#pragma unroll
  for (int mi = 0; mi < 4; mi++) {
    int row = m0 + wm + mi * 16 + (quad << 2);
#pragma unroll
    for (int ni = 0; ni < 4; ni++) {
      int col = n0 + wn + ni * 16 + lane15;
      float bb = bias[col];
#pragma unroll
      for (int r = 0; r < 4; r++) {
        float v = acc[mi][ni][r] + bb;
        if (BF16OUT) ((u16*)Cv)[(size_t)(row + r) * N + col] = f2bf(v);
        else         ((float*)Cv)[(size_t)(row + r) * N + col] = v;
      }
    }
  }
}

// ---------------- Wd GEMM with hi/lo bf16 output ----------------------------
__global__ __launch_bounds__(256) void gemm_wd_hilo(
    const u16* __restrict__ A, const u16* __restrict__ BT,
    const float* __restrict__ bias, u16* __restrict__ Ch, u16* __restrict__ Cl,
    int M, int N, int K) {
  __shared__ u16 As[128 * BK];
  __shared__ u16 Bs[128 * BK];
  const int tid = threadIdx.x;
  const int lane = tid & 63, w = tid >> 6;
  const int m0 = blockIdx.y * 128, n0 = blockIdx.x * 128;
  const int wm = (w & 1) * 64, wn = (w >> 1) * 64;
  const int srow = lane >> 3, schunk = lane & 7;
  const int lane15 = lane & 15, quad = lane >> 4;
  floatx4 acc[4][4] = {};
  for (int kt = 0; kt < K; kt += BK) {
    __syncthreads();
#pragma unroll
    for (int i = 0; i < 4; i++) {
      int R = (w * 4 + i) * 8 + srow;
      int cg = schunk ^ (R & 7);
      async16((char*)As + (w * 4 + i) * 1024,
              (const char*)A + ((size_t)(m0 + R) * K + kt) * 2 + cg * 16);
      async16((char*)Bs + (w * 4 + i) * 1024,
              (const char*)BT + ((size_t)(n0 + R) * K + kt) * 2 + cg * 16);
    }
    __syncthreads();
#pragma unroll
    for (int kk = 0; kk < 2; kk++) {
      bf16x8 af[4], bfr[4];
#pragma unroll
      for (int mi = 0; mi < 4; mi++) af[mi] = fragld(As, wm + mi * 16 + lane15, kk, quad);
#pragma unroll
      for (int ni = 0; ni < 4; ni++) bfr[ni] = fragld(Bs, wn + ni * 16 + lane15, kk, quad);
#pragma unroll
      for (int mi = 0; mi < 4; mi++)
#pragma unroll
        for (int ni = 0; ni < 4; ni++)
          acc[mi][ni] = __builtin_amdgcn_mfma_f32_16x16x32_bf16(
              af[mi], bfr[ni], acc[mi][ni], 0, 0, 0);
    }
  }
#pragma unroll
  for (int mi = 0; mi < 4; mi++) {
    int row = m0 + wm + mi * 16 + (quad << 2);
#pragma unroll
    for (int ni = 0; ni < 4; ni++) {
      int col = n0 + wn + ni * 16 + lane15;
      float bb = bias[col];
#pragma unroll
      for (int r = 0; r < 4; r++) {
        float v = acc[mi][ni][r] + bb;
        u16 hh, ll;
        hilo(v, hh, ll);
        size_t idx = (size_t)(row + r) * N + col;
        Ch[idx] = hh;
        Cl[idx] = ll;
      }
    }
  }
}

// ---------------- fused ctx v2: Wu register-resident, wave-owns-c-columns ---
// kv MFMA: wave w owns c-tiles {base+w&1, base+w&1+2} (k-waves 0,1 hold rope
// pairs d/d+32; v-waves 2,3 hold v). Wu hi/lo frags live in 64 VGPRs, loaded
// once per block from global (L2). C panel staged full-K (64x128 hi+lo, 32 KB)
// once per tile via async16. Operand values and MFMA accumulation order are
// identical to v1 (bitwise-same k/v/ctx); only ksum association order differs.
__global__ __launch_bounds__(256, 2) void ctx_fused(
    const u16* __restrict__ Chi, const u16* __restrict__ Clo,
    const u16* __restrict__ Wuh, const u16* __restrict__ Wul,
    const float* __restrict__ bu, const float2* __restrict__ cs,
    float* __restrict__ ctxp, float* __restrict__ ksump) {
  __shared__ __align__(16) u16 Ah_[64 * 128];   // 16 KB, 256-B rows
  __shared__ __align__(16) u16 Al_[64 * 128];   // 16 KB
  __shared__ __align__(16) u16 Kh_[64 * 64], Kl_[64 * 64];  // 8 KB each, 128-B rows
  __shared__ __align__(16) u16 Vh_[64 * 64], Vl_[64 * 64];
  __shared__ float bus[128];
  __shared__ float ksl[256];
  const int tid = threadIdx.x;
  const int lane = tid & 63, w = tid >> 6;
  const int lane15 = lane & 15, quad = lane >> 4;
  const int chunk = blockIdx.x, bh = blockIdx.y;
  const int b = bh >> 3, h = bh & 7;
  if (tid < 128) bus[tid] = bu[h * RANK + tid];

  // Wu fragments -> registers: [rp][kk][ct], ct over this wave's 2 c-tiles.
  bf16x8 wuh[2][2][2], wul[2][2][2];
  {
    const int cb = (w >> 1) * 4 + (w & 1);      // ctile = cb + ct*2
#pragma unroll
    for (int rp = 0; rp < 2; rp++)
#pragma unroll
      for (int kk = 0; kk < 2; kk++)
#pragma unroll
        for (int ct = 0; ct < 2; ct++) {
          size_t off = (size_t)(h * 128 + (cb + ct * 2) * 16 + lane15) * RANK
                       + rp * 64 + kk * 32 + quad * 8;
          wuh[rp][kk][ct] = *(const bf16x8*)(Wuh + off);
          wul[rp][kk][ct] = *(const bf16x8*)(Wul + off);
        }
  }

  const int t00 = chunk * 512;
  auto stageA = [&](int t0) {
#pragma unroll
    for (int i = 0; i < 4; i++) {
      int R = i * 16 + w * 4 + (lane >> 4);     // row 0..63, 4 rows/wave/iter
      int cg = (lane & 15) ^ (R & 7);           // src chunk for XOR swizzle
      size_t aoff = ((size_t)(b * T_SEQ + t0 + R) * RANK + cg * 8) * 2;
      async16((char*)Ah_ + (i * 16 + w * 4) * 256, (const char*)Chi + aoff);
      async16((char*)Al_ + (i * 16 + w * 4) * 256, (const char*)Clo + aoff);
    }
  };

  floatx4 acc2[4] = {};
  float ks0 = 0.f, ks1 = 0.f;
  stageA(t00);
  for (int tile = 0; tile < 8; tile++) {
    const int t0 = t00 + tile * 64;
    __syncthreads();   // B0: A(t) staged (vmcnt drained); prev ctx done with K/V
    floatx4 acc[4][2] = {};
#pragma unroll
    for (int rp = 0; rp < 2; rp++)
#pragma unroll
      for (int kk = 0; kk < 2; kk++) {
        const int gc = rp * 8 + kk * 4 + quad;
        bf16x8 ah[4], al[4];
#pragma unroll
        for (int tt = 0; tt < 4; tt++) {
          ah[tt] = fragldA(Ah_, tt * 16 + lane15, gc);
          al[tt] = fragldA(Al_, tt * 16 + lane15, gc);
        }
#pragma unroll
        for (int tt = 0; tt < 4; tt++)
#pragma unroll
          for (int ct = 0; ct < 2; ct++) {
            acc[tt][ct] = __builtin_amdgcn_mfma_f32_16x16x32_bf16(
                ah[tt], wuh[rp][kk][ct], acc[tt][ct], 0, 0, 0);
            acc[tt][ct] = __builtin_amdgcn_mfma_f32_16x16x32_bf16(
                ah[tt], wul[rp][kk][ct], acc[tt][ct], 0, 0, 0);
            acc[tt][ct] = __builtin_amdgcn_mfma_f32_16x16x32_bf16(
                al[tt], wuh[rp][kk][ct], acc[tt][ct], 0, 0, 0);
            acc[tt][ct] = __builtin_amdgcn_mfma_f32_16x16x32_bf16(
                al[tt], wul[rp][kk][ct], acc[tt][ct], 0, 0, 0);
          }
      }
    __syncthreads();   // B1a: all waves done reading A(t) -> A reusable
    if (tile < 7) stageA(t0 + 64);   // DMA hides under epilogue + ctx MFMA
    // epilogue: k-waves rope/elu/hilo their d and d+32 columns; v-waves bias/hilo
    if (w < 2) {
      const int d = w * 16 + lane15;            // 0..31
      const float b1 = bus[d], b2 = bus[d + 32];
#pragma unroll
      for (int tt = 0; tt < 4; tt++) {
        const int tg = t0 + tt * 16 + (quad << 2);
        ushort4 khl, kll, khh, klh;
        float s0 = 0.f, s1 = 0.f;
#pragma unroll
        for (int r = 0; r < 4; r++) {
          float2 sc = cs[(size_t)(tg + r) * 32 + d];
          float x1 = acc[tt][0][r] + b1;
          float x2 = acc[tt][1][r] + b2;
          float k1 = elu1(x1 * sc.x - x2 * sc.y);
          float k2 = elu1(x1 * sc.y + x2 * sc.x);
          s0 += k1; s1 += k2;
          u16 hh, ll;
          hilo(k1, hh, ll); ((u16*)&khl)[r] = hh; ((u16*)&kll)[r] = ll;
          hilo(k2, hh, ll); ((u16*)&khh)[r] = hh; ((u16*)&klh)[r] = ll;
        }
        ks0 += s0; ks1 += s1;
        const int chq = tt * 2 + (quad >> 1);
        const int off = d * 128 + (((chq ^ (d & 7)) << 4) | ((quad & 1) << 3));
        *(ushort4*)((char*)Kh_ + off)            = khl;
        *(ushort4*)((char*)Kl_ + off)            = kll;
        *(ushort4*)((char*)Kh_ + off + 32 * 128) = khh;
        *(ushort4*)((char*)Kl_ + off + 32 * 128) = klh;
      }
    } else {
      const int e = (w - 2) * 16 + lane15;      // 0..31
#pragma unroll
      for (int ct = 0; ct < 2; ct++) {
        const float be = bus[64 + e + ct * 32];
#pragma unroll
        for (int tt = 0; tt < 4; tt++) {
          ushort4 vh4, vl4;
#pragma unroll
          for (int r = 0; r < 4; r++) {
            u16 hh, ll;
            hilo(acc[tt][ct][r] + be, hh, ll);
            ((u16*)&vh4)[r] = hh; ((u16*)&vl4)[r] = ll;
          }
          const int chq = tt * 2 + (quad >> 1);
          const int off = (e + ct * 32) * 128 +
                          (((chq ^ (e & 7)) << 4) | ((quad & 1) << 3));
          *(ushort4*)((char*)Vh_ + off) = vh4;
          *(ushort4*)((char*)Vl_ + off) = vl4;
        }
      }
    }
    __syncthreads();   // B1b: K/V visible to all waves
    // ctx MFMA: wave w -> d-tile w (16 d) x 64 e; K = 64 t; 4-term
#pragma unroll
    for (int kk = 0; kk < 2; kk++) {
      bf16x8 kh8 = fragld(Kh_, w * 16 + lane15, kk, quad);
      bf16x8 kl8 = fragld(Kl_, w * 16 + lane15, kk, quad);
#pragma unroll
      for (int ni = 0; ni < 4; ni++) {
        bf16x8 vh8 = fragld(Vh_, ni * 16 + lane15, kk, quad);
        bf16x8 vl8 = fragld(Vl_, ni * 16 + lane15, kk, quad);
        acc2[ni] = __builtin_amdgcn_mfma_f32_16x16x32_bf16(kh8, vh8, acc2[ni], 0, 0, 0);
        acc2[ni] = __builtin_amdgcn_mfma_f32_16x16x32_bf16(kh8, vl8, acc2[ni], 0, 0, 0);
        acc2[ni] = __builtin_amdgcn_mfma_f32_16x16x32_bf16(kl8, vh8, acc2[ni], 0, 0, 0);
        acc2[ni] = __builtin_amdgcn_mfma_f32_16x16x32_bf16(kl8, vl8, acc2[ni], 0, 0, 0);
      }
    }
  }
  const size_t obase = ((size_t)bh * NCHUNK + chunk) * 4096;
#pragma unroll
  for (int ni = 0; ni < 4; ni++)
#pragma unroll
    for (int r = 0; r < 4; r++)
      ctxp[obase + (size_t)(w * 16 + (quad << 2) + r) * 64 + ni * 16 + lane15] = acc2[ni][r];
  // ksum: k-waves hold per-quad partials for d = w*16+lane15 (+32)
  if (w < 2) {
    ksl[w * 128 + lane]      = ks0;
    ksl[w * 128 + 64 + lane] = ks1;
  }
  __syncthreads();
  if (tid < 64) {
    const int d = tid;
    const int wk = (d >> 4) & 1, hi = d >> 5, l15 = d & 15;
    float s = 0.f;
#pragma unroll
    for (int q = 0; q < 4; q++) s += ksl[wk * 128 + hi * 64 + q * 16 + l15];
    ksump[(bh * NCHUNK + chunk) * 64 + d] = s;
  }
}

// ---------------- reduce chunk partials ------------------------------------
__global__ __launch_bounds__(256) void reduce_kernel(
    const float* __restrict__ ctxp, const float* __restrict__ ksump,
    float* __restrict__ ctx, float* __restrict__ ksum) {
  int bh = blockIdx.x, tid = threadIdx.x;
  for (int i = tid; i < 4096; i += 256) {
    float s = 0.f;
    for (int c = 0; c < NCHUNK; c++) s += ctxp[(size_t)(bh * NCHUNK + c) * 4096 + i];
    ctx[(size_t)bh * 4096 + i] = s;
  }
  if (tid < 64) {
    float s = 0.f;
    for (int c = 0; c < NCHUNK; c++) s += ksump[(bh * NCHUNK + c) * 64 + tid];
    ksum[bh * 64 + tid] = s;
  }
}

// ---------------- out = rope/elu(q) @ ctx, normalized; bf16 out (r6-proven) -
__global__ __launch_bounds__(256) void out_kernel(
    const float* __restrict__ Q, const float* __restrict__ ctx,
    const float* __restrict__ ksum, const float2* __restrict__ cs,
    u16* __restrict__ attn) {
  __shared__ __align__(16) float Qs[128 * 68];   // [t][d]
  __shared__ __align__(16) float Cts[64 * 68];   // [d][e]
  __shared__ float ks[64];
  __shared__ float zs[128];
  const int tid = threadIdx.x;
  const int tt0 = blockIdx.x * 128;
  const int bh = blockIdx.y;
  const int b = bh >> 3, h = bh & 7;
  for (int i = tid; i < 4096; i += 256)
    Cts[(i >> 6) * 68 + (i & 63)] = ctx[(size_t)bh * 4096 + i];
  if (tid < 64) ks[tid] = ksum[bh * 64 + tid];
  for (int i = tid; i < 8192; i += 256) {
    int t = i >> 6, d = i & 63;
    Qs[t * 68 + d] = Q[(size_t)(b * T_SEQ + tt0 + t) * DM + h * HD + d];
  }
  __syncthreads();
  for (int i = tid; i < 128 * 32; i += 256) {
    int t = i >> 5, d = i & 31;
    float x1 = Qs[t * 68 + d], x2 = Qs[t * 68 + d + 32];
    float2 sc = cs[(size_t)(tt0 + t) * 32 + d];
    float r1 = x1 * sc.x - x2 * sc.y;
    float r2 = x1 * sc.y + x2 * sc.x;
    Qs[t * 68 + d]      = (r1 > 0.f) ? r1 + 1.f : expf(r1);
    Qs[t * 68 + d + 32] = (r2 > 0.f) ? r2 + 1.f : expf(r2);
  }
  __syncthreads();
  if (tid < 128) {
    float z = 0.f;
#pragma unroll 8
    for (int d = 0; d < 64; d++) z += Qs[tid * 68 + d] * ks[d];
    zs[tid] = 1.f / (z + 1e-6f);
  }
  __syncthreads();
  const int tx = tid & 15, ty = tid >> 4;   // e = tx*4+j, t = ty*8+i
  float acc[8][4] = {};
  for (int d = 0; d < 64; d++) {
    const float4 c4 = *(const float4*)&Cts[d * 68 + tx * 4];
#pragma unroll
    for (int i = 0; i < 8; i++) {
      float q = Qs[(ty * 8 + i) * 68 + d];
      acc[i][0] += q * c4.x; acc[i][1] += q * c4.y;
      acc[i][2] += q * c4.z; acc[i][3] += q * c4.w;
    }
  }
#pragma unroll
  for (int i = 0; i < 8; i++) {
    int t = ty * 8 + i;
    float zz = zs[t];
    ushort4 o;
    o.x = f2bf(acc[i][0] * zz); o.y = f2bf(acc[i][1] * zz);
    o.z = f2bf(acc[i][2] * zz); o.w = f2bf(acc[i][3] * zz);
    *(ushort4*)&attn[(size_t)(b * T_SEQ + tt0 + t) * DM + h * HD + tx * 4] = o;
  }
}

// ---------------- launch ----------------------------------------------------
extern "C" void kernel_launch(void* const* d_in, const int* in_sizes, int n_in,
                              void* d_out, int out_size, void* d_ws, size_t ws_size,
                              hipStream_t stream) {
  const float* x  = (const float*)d_in[0];
  const float* Wq = (const float*)d_in[1];
  const float* bq = (const float*)d_in[2];
  const float* Wd = (const float*)d_in[3];
  const float* bd = (const float*)d_in[4];
  const float* Wu = (const float*)d_in[5];
  const float* bu = (const float*)d_in[6];
  const float* Wo = (const float*)d_in[7];
  const float* bo = (const float*)d_in[8];
  float* out = (float*)d_out;

  float* ws = (float*)d_ws;
  size_t o_cs   = 0;
  size_t o_Q    = o_cs + (size_t)T_SEQ * 32 * 2;            // 262144
  size_t o_Chi  = o_Q + (size_t)MTOT * DM;                  // Q fp32 (raw x@Wq+bq)
  size_t o_Clo  = o_Chi + (size_t)MTOT * RANK / 2;          // C hi u16
  size_t o_ctxp = o_Clo + (size_t)MTOT * RANK / 2;          // C lo u16
  size_t o_ksp  = o_ctxp + (size_t)64 * NCHUNK * 4096;
  size_t o_ctx  = o_ksp + (size_t)64 * NCHUNK * 64;
  size_t o_ks   = o_ctx + (size_t)64 * 4096;
  size_t o_xbf  = o_ks + 64 * 64;
  size_t o_wqT  = o_xbf + (size_t)MTOT * DM / 2;            // x_bf / attn_bf alias
  size_t o_wdT  = o_wqT + (size_t)DM * DM / 2;
  size_t o_woT  = o_wdT + (size_t)DM * RANK / 2;
  size_t o_wuTh = o_woT + (size_t)DM * DM / 2;
  size_t o_wuTl = o_wuTh + (size_t)(2 * DM) * RANK / 2;
  size_t total  = o_wuTl + (size_t)(2 * DM) * RANK / 2;     // ~32.4M floats = 130 MB
  if (ws_size < total * sizeof(float)) return;  // loud failure instead of corruption

  float2* cs  = (float2*)(ws + o_cs);
  float* Qb   = ws + o_Q;
  u16* Chi    = (u16*)(ws + o_Chi);
  u16* Clo    = (u16*)(ws + o_Clo);
  float* ctxp = ws + o_ctxp;
  float* ksp  = ws + o_ksp;
  float* ctxf = ws + o_ctx;
  float* ksf  = ws + o_ks;
  u16* x_bf   = (u16*)(ws + o_xbf);
  u16* attn_bf= x_bf;                 // alias: x_bf dead after the two input GEMMs
  u16* WqT    = (u16*)(ws + o_wqT);
  u16* WdT    = (u16*)(ws + o_wdT);
  u16* WoT    = (u16*)(ws + o_woT);
  u16* WuTh   = (u16*)(ws + o_wuTh);
  u16* WuTl   = (u16*)(ws + o_wuTl);

  cs_kernel<<<(T_SEQ * 32 + 255) / 256, 256, 0, stream>>>(cs);
  pack_bf16<<<(MTOT * DM / 4) / 256, 256, 0, stream>>>(x, x_bf);
  transpose_cast<<<dim3(DM / 32, DM / 32), 256, 0, stream>>>(Wq, WqT, DM, DM);
  transpose_cast<<<dim3(DM / 32, RANK / 32), 256, 0, stream>>>(Wd, WdT, DM, RANK);
  transpose_cast<<<dim3(DM / 32, DM / 32), 256, 0, stream>>>(Wo, WoT, DM, DM);
  transpose_cast_hilo<<<dim3(RANK / 32, (2 * DM) / 32), 256, 0, stream>>>(
      Wu, WuTh, WuTl, RANK, 2 * DM);

  gemm_bf16_bt<false><<<dim3(DM / 128, MTOT / 128), 256, 0, stream>>>(
      x_bf, WqT, bq, Qb, MTOT, DM, DM);
  gemm_wd_hilo<<<dim3(RANK / 128, MTOT / 128), 256, 0, stream>>>(
      x_bf, WdT, bd, Chi, Clo, MTOT, RANK, DM);
  ctx_fused<<<dim3(NCHUNK, BATCH * NH), 256, 0, stream>>>(
      Chi, Clo, WuTh, WuTl, bu, cs, ctxp, ksp);
  reduce_kernel<<<BATCH * NH, 256, 0, stream>>>(ctxp, ksp, ctxf, ksf);
  out_kernel<<<dim3(T_SEQ / 128, BATCH * NH), 256, 0, stream>>>(Qb, ctxf, ksf, cs, attn_bf);
  gemm_bf16_bt<false><<<dim3(DM / 128, MTOT / 128), 256, 0, stream>>>(
      attn_bf, WoT, bo, out, MTOT, DM, DM);
}

// Round 5
// 324.722 us; speedup vs baseline: 1.0250x; 1.0250x over previous
//
#include <hip/hip_runtime.h>
#include <math.h>

#define T_SEQ 4096
#define BATCH 8
#define DM    512
#define NH    8
#define HD    64
#define RANK  128
#define NCHUNK 16
#define MTOT  (BATCH * T_SEQ)    /* 32768 */
#define BK 64

typedef unsigned int u32;
typedef unsigned short u16;
using bf16x8  = __attribute__((ext_vector_type(8))) __bf16;
using floatx4 = __attribute__((ext_vector_type(4))) float;

__device__ __forceinline__ u16 f2bf(float f) {   // RNE, finite inputs
  u32 u = __float_as_uint(f);
  u32 r = (u + 0x7FFFu + ((u >> 16) & 1u)) >> 16;
  return (u16)r;
}
// hi/lo bf16 split: f == hi + lo to ~17 mantissa bits
__device__ __forceinline__ void hilo(float f, u16& h, u16& l) {
  h = f2bf(f);
  float hf = __uint_as_float(((u32)h) << 16);
  l = f2bf(f - hf);
}
__device__ __forceinline__ float elu1(float x) {
  return (x > 0.f) ? x + 1.f : expf(x);
}
__device__ __forceinline__ void async16(void* lds, const void* g) {
  __builtin_amdgcn_global_load_lds(
      (const __attribute__((address_space(1))) u32*)g,
      (__attribute__((address_space(3))) u32*)lds, 16, 0, 0);
}
// LDS rows are 128 B (64 u16), 16B-chunk XOR-swizzled by (row&7).
__device__ __forceinline__ bf16x8 fragld(const u16* base, int row, int kk, int quad) {
  int ch = (kk * 4 + quad) ^ (row & 7);
  return *(const bf16x8*)((const char*)base + row * 128 + ch * 16);
}
// LDS rows are 256 B (128 u16), 16 chunks, XOR-swizzled by (row&7) (low 3 bits).
__device__ __forceinline__ bf16x8 fragldA(const u16* base, int row, int gc) {
  int ch = gc ^ (row & 7);
  return *(const bf16x8*)((const char*)base + row * 256 + ch * 16);
}

// ---------------- cos/sin table (double precision, matches np ref) ----------
__global__ void cs_kernel(float2* __restrict__ cs) {
  int i = blockIdx.x * 256 + threadIdx.x;
  if (i >= T_SEQ * 32) return;
  int t = i >> 5, d = i & 31;
  double freq = pow(10000.0, -(double)d / 32.0);
  double a = (double)t * freq;
  cs[i] = make_float2((float)cos(a), (float)sin(a));
}

// ---------------- pack fp32 -> bf16 -----------------------------------------
__global__ __launch_bounds__(256) void pack_bf16(const float* __restrict__ x,
                                                 u16* __restrict__ y) {
  int i = blockIdx.x * 256 + threadIdx.x;
  const float4 v = ((const float4*)x)[i];
  ushort4 o;
  o.x = f2bf(v.x); o.y = f2bf(v.y); o.z = f2bf(v.z); o.w = f2bf(v.w);
  ((ushort4*)y)[i] = o;
}

// ---------------- W (KxN fp32) -> WT (NxK bf16) -----------------------------
__global__ __launch_bounds__(256) void transpose_cast(const float* __restrict__ W,
                                                      u16* __restrict__ WT,
                                                      int K, int N) {
  __shared__ float t[32][33];
  int kb = blockIdx.x * 32, nb = blockIdx.y * 32;
  int tx = threadIdx.x & 31, tg = threadIdx.x >> 5;
#pragma unroll
  for (int i = 0; i < 4; i++)
    t[tg * 4 + i][tx] = W[(size_t)(kb + tg * 4 + i) * N + nb + tx];
  __syncthreads();
#pragma unroll
  for (int i = 0; i < 4; i++)
    WT[(size_t)(nb + tg * 4 + i) * K + kb + tx] = f2bf(t[tx][tg * 4 + i]);
}

// ---------------- W (KxN fp32) -> WT hi/lo (NxK bf16 pair) ------------------
__global__ __launch_bounds__(256) void transpose_cast_hilo(
    const float* __restrict__ W, u16* __restrict__ WTh, u16* __restrict__ WTl,
    int K, int N) {
  __shared__ float t[32][33];
  int kb = blockIdx.x * 32, nb = blockIdx.y * 32;
  int tx = threadIdx.x & 31, tg = threadIdx.x >> 5;
#pragma unroll
  for (int i = 0; i < 4; i++)
    t[tg * 4 + i][tx] = W[(size_t)(kb + tg * 4 + i) * N + nb + tx];
  __syncthreads();
#pragma unroll
  for (int i = 0; i < 4; i++) {
    u16 h, l;
    hilo(t[tx][tg * 4 + i], h, l);
    WTh[(size_t)(nb + tg * 4 + i) * K + kb + tx] = h;
    WTl[(size_t)(nb + tg * 4 + i) * K + kb + tx] = l;
  }
}

// ---------------- bf16 MFMA GEMM: C = A @ BT^T + bias (r1-proven) -----------
template <bool BF16OUT>
__global__ __launch_bounds__(256) void gemm_bf16_bt(
    const u16* __restrict__ A, const u16* __restrict__ BT,
    const float* __restrict__ bias, void* __restrict__ Cv,
    int M, int N, int K) {
  __shared__ u16 As[128 * BK];
  __shared__ u16 Bs[128 * BK];
  const int tid = threadIdx.x;
  const int lane = tid & 63, w = tid >> 6;
  const int m0 = blockIdx.y * 128, n0 = blockIdx.x * 128;
  const int wm = (w & 1) * 64, wn = (w >> 1) * 64;
  const int srow = lane >> 3, schunk = lane & 7;
  const int lane15 = lane & 15, quad = lane >> 4;
  floatx4 acc[4][4] = {};
  for (int kt = 0; kt < K; kt += BK) {
    __syncthreads();
#pragma unroll
    for (int i = 0; i < 4; i++) {
      int R = (w * 4 + i) * 8 + srow;
      int cg = schunk ^ (R & 7);
      async16((char*)As + (w * 4 + i) * 1024,
              (const char*)A + ((size_t)(m0 + R) * K + kt) * 2 + cg * 16);
      async16((char*)Bs + (w * 4 + i) * 1024,
              (const char*)BT + ((size_t)(n0 + R) * K + kt) * 2 + cg * 16);
    }
    __syncthreads();
#pragma unroll
    for (int kk = 0; kk < 2; kk++) {
      bf16x8 af[4], bfr[4];
#pragma unroll
      for (int mi = 0; mi < 4; mi++) af[mi] = fragld(As, wm + mi * 16 + lane15, kk, quad);
#pragma unroll
      for (int ni = 0; ni < 4; ni++) bfr[ni] = fragld(Bs, wn + ni * 16 + lane15, kk, quad);
#pragma unroll
      for (int mi = 0; mi < 4; mi++)
#pragma unroll
        for (int ni = 0; ni < 4; ni++)
          acc[mi][ni] = __builtin_amdgcn_mfma_f32_16x16x32_bf16(
              af[mi], bfr[ni], acc[mi][ni], 0, 0, 0);
    }
  }
#pragma unroll
  for (int mi = 0; mi < 4; mi++) {
    int row = m0 + wm + mi * 16 + (quad << 2);
#pragma unroll
    for (int ni = 0; ni < 4; ni++) {
      int col = n0 + wn + ni * 16 + lane15;
      float bb = bias[col];
#pragma unroll
      for (int r = 0; r < 4; r++) {
        float v = acc[mi][ni][r] + bb;
        if (BF16OUT) ((u16*)Cv)[(size_t)(row + r) * N + col] = f2bf(v);
        else         ((float*)Cv)[(size_t)(row + r) * N + col] = v;
      }
    }
  }
}

// ---------------- Wd GEMM with hi/lo bf16 output ----------------------------
__global__ __launch_bounds__(256) void gemm_wd_hilo(
    const u16* __restrict__ A, const u16* __restrict__ BT,
    const float* __restrict__ bias, u16* __restrict__ Ch, u16* __restrict__ Cl,
    int M, int N, int K) {
  __shared__ u16 As[128 * BK];
  __shared__ u16 Bs[128 * BK];
  const int tid = threadIdx.x;
  const int lane = tid & 63, w = tid >> 6;
  const int m0 = blockIdx.y * 128, n0 = blockIdx.x * 128;
  const int wm = (w & 1) * 64, wn = (w >> 1) * 64;
  const int srow = lane >> 3, schunk = lane & 7;
  const int lane15 = lane & 15, quad = lane >> 4;
  floatx4 acc[4][4] = {};
  for (int kt = 0; kt < K; kt += BK) {
    __syncthreads();
#pragma unroll
    for (int i = 0; i < 4; i++) {
      int R = (w * 4 + i) * 8 + srow;
      int cg = schunk ^ (R & 7);
      async16((char*)As + (w * 4 + i) * 1024,
              (const char*)A + ((size_t)(m0 + R) * K + kt) * 2 + cg * 16);
      async16((char*)Bs + (w * 4 + i) * 1024,
              (const char*)BT + ((size_t)(n0 + R) * K + kt) * 2 + cg * 16);
    }
    __syncthreads();
#pragma unroll
    for (int kk = 0; kk < 2; kk++) {
      bf16x8 af[4], bfr[4];
#pragma unroll
      for (int mi = 0; mi < 4; mi++) af[mi] = fragld(As, wm + mi * 16 + lane15, kk, quad);
#pragma unroll
      for (int ni = 0; ni < 4; ni++) bfr[ni] = fragld(Bs, wn + ni * 16 + lane15, kk, quad);
#pragma unroll
      for (int mi = 0; mi < 4; mi++)
#pragma unroll
        for (int ni = 0; ni < 4; ni++)
          acc[mi][ni] = __builtin_amdgcn_mfma_f32_16x16x32_bf16(
              af[mi], bfr[ni], acc[mi][ni], 0, 0, 0);
    }
  }
#pragma unroll
  for (int mi = 0; mi < 4; mi++) {
    int row = m0 + wm + mi * 16 + (quad << 2);
#pragma unroll
    for (int ni = 0; ni < 4; ni++) {
      int col = n0 + wn + ni * 16 + lane15;
      float bb = bias[col];
#pragma unroll
      for (int r = 0; r < 4; r++) {
        float v = acc[mi][ni][r] + bb;
        u16 hh, ll;
        hilo(v, hh, ll);
        size_t idx = (size_t)(row + r) * N + col;
        Ch[idx] = hh;
        Cl[idx] = ll;
      }
    }
  }
}

// ---------------- fused ctx v3b: 3-term hi/lo, half-tile A staging, 3 blk/CU
// v3 bug fixed: prefetch at hh==1 must stage the NEXT tile's first half
// (t0+64), not t0+96 — pipeline depth is one 32-t half.
__global__ __launch_bounds__(256, 3) void ctx_fused(
    const u16* __restrict__ Chi, const u16* __restrict__ Clo,
    const u16* __restrict__ Wuh, const u16* __restrict__ Wul,
    const float* __restrict__ bu, const float2* __restrict__ cs,
    float* __restrict__ ctxp, float* __restrict__ ksump) {
  __shared__ __align__(16) u16 Ah_[32 * 128];   // 8 KB, 256-B rows (32 t half)
  __shared__ __align__(16) u16 Al_[32 * 128];   // 8 KB
  __shared__ __align__(16) u16 Kh_[64 * 64], Kl_[64 * 64];  // 8 KB each, 128-B rows
  __shared__ __align__(16) u16 Vh_[64 * 64], Vl_[64 * 64];
  __shared__ float bus[128];
  __shared__ float ksl[256];
  const int tid = threadIdx.x;
  const int lane = tid & 63, w = tid >> 6;
  const int lane15 = lane & 15, quad = lane >> 4;
  const int chunk = blockIdx.x, bh = blockIdx.y;
  const int b = bh >> 3, h = bh & 7;
  if (tid < 128) bus[tid] = bu[h * RANK + tid];

  // Wu fragments -> registers: [rp][kk][ct], ct over this wave's 2 c-tiles.
  bf16x8 wuh[2][2][2], wul[2][2][2];
  {
    const int cb = (w >> 1) * 4 + (w & 1);      // ctile = cb + ct*2
#pragma unroll
    for (int rp = 0; rp < 2; rp++)
#pragma unroll
      for (int kk = 0; kk < 2; kk++)
#pragma unroll
        for (int ct = 0; ct < 2; ct++) {
          size_t off = (size_t)(h * 128 + (cb + ct * 2) * 16 + lane15) * RANK
                       + rp * 64 + kk * 32 + quad * 8;
          wuh[rp][kk][ct] = *(const bf16x8*)(Wuh + off);
          wul[rp][kk][ct] = *(const bf16x8*)(Wul + off);
        }
  }

  const int t00 = chunk * (T_SEQ / NCHUNK);     // 256 t per chunk, 4 tiles
  // stage one 32-t half (rows tg0..tg0+31) of Chi/Clo into Ah_/Al_
  auto stageA = [&](int tg0) {
#pragma unroll
    for (int i = 0; i < 2; i++) {
      int R = i * 16 + w * 4 + (lane >> 4);     // row 0..31, 4 rows/wave/iter
      int cg = (lane & 15) ^ (R & 7);           // src chunk for XOR swizzle
      size_t aoff = ((size_t)(b * T_SEQ + tg0 + R) * RANK + cg * 8) * 2;
      async16((char*)Ah_ + (i * 16 + w * 4) * 256, (const char*)Chi + aoff);
      async16((char*)Al_ + (i * 16 + w * 4) * 256, (const char*)Clo + aoff);
    }
  };

  floatx4 acc2[4] = {};
  float ks0 = 0.f, ks1 = 0.f;
  stageA(t00);
  for (int tile = 0; tile < T_SEQ / NCHUNK / 64; tile++) {
    const int t0 = t00 + tile * 64;
#pragma unroll
    for (int hh = 0; hh < 2; hh++) {
      __syncthreads();   // A(half) staged (vmcnt drained); prev ctx done
      floatx4 acc[2][2] = {};
#pragma unroll
      for (int rp = 0; rp < 2; rp++)
#pragma unroll
        for (int kk = 0; kk < 2; kk++) {
          const int gc = rp * 8 + kk * 4 + quad;
          bf16x8 ah[2], al[2];
#pragma unroll
          for (int tt = 0; tt < 2; tt++) {
            ah[tt] = fragldA(Ah_, tt * 16 + lane15, gc);
            al[tt] = fragldA(Al_, tt * 16 + lane15, gc);
          }
#pragma unroll
          for (int tt = 0; tt < 2; tt++)
#pragma unroll
            for (int ct = 0; ct < 2; ct++) {
              acc[tt][ct] = __builtin_amdgcn_mfma_f32_16x16x32_bf16(
                  ah[tt], wuh[rp][kk][ct], acc[tt][ct], 0, 0, 0);
              acc[tt][ct] = __builtin_amdgcn_mfma_f32_16x16x32_bf16(
                  ah[tt], wul[rp][kk][ct], acc[tt][ct], 0, 0, 0);
              acc[tt][ct] = __builtin_amdgcn_mfma_f32_16x16x32_bf16(
                  al[tt], wuh[rp][kk][ct], acc[tt][ct], 0, 0, 0);
            }
        }
      __syncthreads();   // all waves done reading A(half) -> A reusable
      // stage next half (one half ahead): (tile,hh=1) needs t0+32;
      // (tile+1,hh=0) needs t0+64.
      if (hh == 0) stageA(t0 + 32);
      else if (tile < T_SEQ / NCHUNK / 64 - 1) stageA(t0 + 64);
      const int tbase = t0 + hh * 32;
      // epilogue: k-waves rope/elu/hilo; v-waves bias/hilo. t-rows of this half.
      if (w < 2) {
        const int d = w * 16 + lane15;            // 0..31
        const float b1 = bus[d], b2 = bus[d + 32];
#pragma unroll
        for (int tt = 0; tt < 2; tt++) {
          const int tg = tbase + tt * 16 + (quad << 2);
          ushort4 khl, kll, khh, klh;
          float s0 = 0.f, s1 = 0.f;
#pragma unroll
          for (int r = 0; r < 4; r++) {
            float2 sc = cs[(size_t)(tg + r) * 32 + d];
            float x1 = acc[tt][0][r] + b1;
            float x2 = acc[tt][1][r] + b2;
            float k1 = elu1(x1 * sc.x - x2 * sc.y);
            float k2 = elu1(x1 * sc.y + x2 * sc.x);
            s0 += k1; s1 += k2;
            u16 hh_, ll_;
            hilo(k1, hh_, ll_); ((u16*)&khl)[r] = hh_; ((u16*)&kll)[r] = ll_;
            hilo(k2, hh_, ll_); ((u16*)&khh)[r] = hh_; ((u16*)&klh)[r] = ll_;
          }
          ks0 += s0; ks1 += s1;
          const int chq = hh * 4 + tt * 2 + (quad >> 1);
          const int off = d * 128 + (((chq ^ (d & 7)) << 4) | ((quad & 1) << 3));
          *(ushort4*)((char*)Kh_ + off)            = khl;
          *(ushort4*)((char*)Kl_ + off)            = kll;
          *(ushort4*)((char*)Kh_ + off + 32 * 128) = khh;
          *(ushort4*)((char*)Kl_ + off + 32 * 128) = klh;
        }
      } else {
        const int e = (w - 2) * 16 + lane15;      // 0..31
#pragma unroll
        for (int ct = 0; ct < 2; ct++) {
          const float be = bus[64 + e + ct * 32];
#pragma unroll
          for (int tt = 0; tt < 2; tt++) {
            ushort4 vh4, vl4;
#pragma unroll
            for (int r = 0; r < 4; r++) {
              u16 hh_, ll_;
              hilo(acc[tt][ct][r] + be, hh_, ll_);
              ((u16*)&vh4)[r] = hh_; ((u16*)&vl4)[r] = ll_;
            }
            const int chq = hh * 4 + tt * 2 + (quad >> 1);
            const int off = (e + ct * 32) * 128 +
                            (((chq ^ (e & 7)) << 4) | ((quad & 1) << 3));
            *(ushort4*)((char*)Vh_ + off) = vh4;
            *(ushort4*)((char*)Vl_ + off) = vl4;
          }
        }
      }
    }
    __syncthreads();   // K/V (full 64 t) visible to all waves
    // ctx MFMA: wave w -> d-tile w (16 d) x 64 e; K = 64 t; 3-term
#pragma unroll
    for (int kk = 0; kk < 2; kk++) {
      bf16x8 kh8 = fragld(Kh_, w * 16 + lane15, kk, quad);
      bf16x8 kl8 = fragld(Kl_, w * 16 + lane15, kk, quad);
#pragma unroll
      for (int ni = 0; ni < 4; ni++) {
        bf16x8 vh8 = fragld(Vh_, ni * 16 + lane15, kk, quad);
        bf16x8 vl8 = fragld(Vl_, ni * 16 + lane15, kk, quad);
        acc2[ni] = __builtin_amdgcn_mfma_f32_16x16x32_bf16(kh8, vh8, acc2[ni], 0, 0, 0);
        acc2[ni] = __builtin_amdgcn_mfma_f32_16x16x32_bf16(kh8, vl8, acc2[ni], 0, 0, 0);
        acc2[ni] = __builtin_amdgcn_mfma_f32_16x16x32_bf16(kl8, vh8, acc2[ni], 0, 0, 0);
      }
    }
  }
  const size_t obase = ((size_t)bh * NCHUNK + chunk) * 4096;
#pragma unroll
  for (int ni = 0; ni < 4; ni++)
#pragma unroll
    for (int r = 0; r < 4; r++)
      ctxp[obase + (size_t)(w * 16 + (quad << 2) + r) * 64 + ni * 16 + lane15] = acc2[ni][r];
  // ksum: k-waves hold per-quad partials for d = w*16+lane15 (+32)
  if (w < 2) {
    ksl[w * 128 + lane]      = ks0;
    ksl[w * 128 + 64 + lane] = ks1;
  }
  __syncthreads();
  if (tid < 64) {
    const int d = tid;
    const int wk = (d >> 4) & 1, hi = d >> 5, l15 = d & 15;
    float s = 0.f;
#pragma unroll
    for (int q = 0; q < 4; q++) s += ksl[wk * 128 + hi * 64 + q * 16 + l15];
    ksump[(bh * NCHUNK + chunk) * 64 + d] = s;
  }
}

// ---------------- reduce chunk partials ------------------------------------
__global__ __launch_bounds__(256) void reduce_kernel(
    const float* __restrict__ ctxp, const float* __restrict__ ksump,
    float* __restrict__ ctx, float* __restrict__ ksum) {
  int bh = blockIdx.x, tid = threadIdx.x;
  for (int i = tid; i < 4096; i += 256) {
    float s = 0.f;
    for (int c = 0; c < NCHUNK; c++) s += ctxp[(size_t)(bh * NCHUNK + c) * 4096 + i];
    ctx[(size_t)bh * 4096 + i] = s;
  }
  if (tid < 64) {
    float s = 0.f;
    for (int c = 0; c < NCHUNK; c++) s += ksump[(bh * NCHUNK + c) * 64 + tid];
    ksum[bh * 64 + tid] = s;
  }
}

// ---------------- out = rope/elu(q) @ ctx, normalized; bf16 out (r6-proven) -
__global__ __launch_bounds__(256) void out_kernel(
    const float* __restrict__ Q, const float* __restrict__ ctx,
    const float* __restrict__ ksum, const float2* __restrict__ cs,
    u16* __restrict__ attn) {
  __shared__ __align__(16) float Qs[128 * 68];   // [t][d]
  __shared__ __align__(16) float Cts[64 * 68];   // [d][e]
  __shared__ float ks[64];
  __shared__ float zs[128];
  const int tid = threadIdx.x;
  const int tt0 = blockIdx.x * 128;
  const int bh = blockIdx.y;
  const int b = bh >> 3, h = bh & 7;
  for (int i = tid; i < 4096; i += 256)
    Cts[(i >> 6) * 68 + (i & 63)] = ctx[(size_t)bh * 4096 + i];
  if (tid < 64) ks[tid] = ksum[bh * 64 + tid];
  for (int i = tid; i < 8192; i += 256) {
    int t = i >> 6, d = i & 63;
    Qs[t * 68 + d] = Q[(size_t)(b * T_SEQ + tt0 + t) * DM + h * HD + d];
  }
  __syncthreads();
  for (int i = tid; i < 128 * 32; i += 256) {
    int t = i >> 5, d = i & 31;
    float x1 = Qs[t * 68 + d], x2 = Qs[t * 68 + d + 32];
    float2 sc = cs[(size_t)(tt0 + t) * 32 + d];
    float r1 = x1 * sc.x - x2 * sc.y;
    float r2 = x1 * sc.y + x2 * sc.x;
    Qs[t * 68 + d]      = (r1 > 0.f) ? r1 + 1.f : expf(r1);
    Qs[t * 68 + d + 32] = (r2 > 0.f) ? r2 + 1.f : expf(r2);
  }
  __syncthreads();
  if (tid < 128) {
    float z = 0.f;
#pragma unroll 8
    for (int d = 0; d < 64; d++) z += Qs[tid * 68 + d] * ks[d];
    zs[tid] = 1.f / (z + 1e-6f);
  }
  __syncthreads();
  const int tx = tid & 15, ty = tid >> 4;   // e = tx*4+j, t = ty*8+i
  float acc[8][4] = {};
  for (int d = 0; d < 64; d++) {
    const float4 c4 = *(const float4*)&Cts[d * 68 + tx * 4];
#pragma unroll
    for (int i = 0; i < 8; i++) {
      float q = Qs[(ty * 8 + i) * 68 + d];
      acc[i][0] += q * c4.x; acc[i][1] += q * c4.y;
      acc[i][2] += q * c4.z; acc[i][3] += q * c4.w;
    }
  }
#pragma unroll
  for (int i = 0; i < 8; i++) {
    int t = ty * 8 + i;
    float zz = zs[t];
    ushort4 o;
    o.x = f2bf(acc[i][0] * zz); o.y = f2bf(acc[i][1] * zz);
    o.z = f2bf(acc[i][2] * zz); o.w = f2bf(acc[i][3] * zz);
    *(ushort4*)&attn[(size_t)(b * T_SEQ + tt0 + t) * DM + h * HD + tx * 4] = o;
  }
}

// ---------------- launch ----------------------------------------------------
extern "C" void kernel_launch(void* const* d_in, const int* in_sizes, int n_in,
                              void* d_out, int out_size, void* d_ws, size_t ws_size,
                              hipStream_t stream) {
  const float* x  = (const float*)d_in[0];
  const float* Wq = (const float*)d_in[1];
  const float* bq = (const float*)d_in[2];
  const float* Wd = (const float*)d_in[3];
  const float* bd = (const float*)d_in[4];
  const float* Wu = (const float*)d_in[5];
  const float* bu = (const float*)d_in[6];
  const float* Wo = (const float*)d_in[7];
  const float* bo = (const float*)d_in[8];
  float* out = (float*)d_out;

  float* ws = (float*)d_ws;
  size_t o_cs   = 0;
  size_t o_Q    = o_cs + (size_t)T_SEQ * 32 * 2;            // 262144
  size_t o_Chi  = o_Q + (size_t)MTOT * DM;                  // Q fp32 (raw x@Wq+bq)
  size_t o_Clo  = o_Chi + (size_t)MTOT * RANK / 2;          // C hi u16
  size_t o_ksp  = o_Clo + (size_t)MTOT * RANK / 2;          // C lo u16
  size_t o_ctx  = o_ksp + (size_t)64 * NCHUNK * 64;
  size_t o_ks   = o_ctx + (size_t)64 * 4096;
  size_t o_xbf  = o_ks + 64 * 64;
  size_t o_wqT  = o_xbf + (size_t)MTOT * DM / 2;            // x_bf/attn_bf/ctxp alias
  size_t o_wdT  = o_wqT + (size_t)DM * DM / 2;
  size_t o_woT  = o_wdT + (size_t)DM * RANK / 2;
  size_t o_wuTh = o_woT + (size_t)DM * DM / 2;
  size_t o_wuTl = o_wuTh + (size_t)(2 * DM) * RANK / 2;
  size_t total  = o_wuTl + (size_t)(2 * DM) * RANK / 2;
  if (ws_size < total * sizeof(float)) return;  // loud failure instead of corruption

  float2* cs  = (float2*)(ws + o_cs);
  float* Qb   = ws + o_Q;
  u16* Chi    = (u16*)(ws + o_Chi);
  u16* Clo    = (u16*)(ws + o_Clo);
  float* ksp  = ws + o_ksp;
  float* ctxf = ws + o_ctx;
  float* ksf  = ws + o_ks;
  u16* x_bf   = (u16*)(ws + o_xbf);
  u16* attn_bf= x_bf;                 // alias: x_bf dead after the two input GEMMs
  // ctxp aliases the x_bf region too: x_bf is dead before ctx_fused writes ctxp,
  // and ctxp is fully consumed by reduce_kernel before out_kernel writes attn_bf.
  // sizes: ctxp = 64*NCHUNK*4096 floats = 4.19M <= x_bf region 8.39M floats.
  float* ctxp = ws + o_xbf;
  u16* WqT    = (u16*)(ws + o_wqT);
  u16* WdT    = (u16*)(ws + o_wdT);
  u16* WoT    = (u16*)(ws + o_woT);
  u16* WuTh   = (u16*)(ws + o_wuTh);
  u16* WuTl   = (u16*)(ws + o_wuTl);

  cs_kernel<<<(T_SEQ * 32 + 255) / 256, 256, 0, stream>>>(cs);
  pack_bf16<<<(MTOT * DM / 4) / 256, 256, 0, stream>>>(x, x_bf);
  transpose_cast<<<dim3(DM / 32, DM / 32), 256, 0, stream>>>(Wq, WqT, DM, DM);
  transpose_cast<<<dim3(DM / 32, RANK / 32), 256, 0, stream>>>(Wd, WdT, DM, RANK);
  transpose_cast<<<dim3(DM / 32, DM / 32), 256, 0, stream>>>(Wo, WoT, DM, DM);
  transpose_cast_hilo<<<dim3(RANK / 32, (2 * DM) / 32), 256, 0, stream>>>(
      Wu, WuTh, WuTl, RANK, 2 * DM);

  gemm_bf16_bt<false><<<dim3(DM / 128, MTOT / 128), 256, 0, stream>>>(
      x_bf, WqT, bq, Qb, MTOT, DM, DM);
  gemm_wd_hilo<<<dim3(RANK / 128, MTOT / 128), 256, 0, stream>>>(
      x_bf, WdT, bd, Chi, Clo, MTOT, RANK, DM);
  ctx_fused<<<dim3(NCHUNK, BATCH * NH), 256, 0, stream>>>(
      Chi, Clo, WuTh, WuTl, bu, cs, ctxp, ksp);
  reduce_kernel<<<BATCH * NH, 256, 0, stream>>>(ctxp, ksp, ctxf, ksf);
  out_kernel<<<dim3(T_SEQ / 128, BATCH * NH), 256, 0, stream>>>(Qb, ctxf, ksf, cs, attn_bf);
  gemm_bf16_bt<false><<<dim3(DM / 128, MTOT / 128), 256, 0, stream>>>(
      attn_bf, WoT, bo, out, MTOT, DM, DM);
}